// Round 11
// baseline (473.811 us; speedup 1.0000x reference)
//
#include <hip/hip_runtime.h>
#include <hip/hip_fp16.h>

#define IN_C  256
#define HID_C 128
#define OUT_C 2
#define BSH   7                    // nodes per bucket = 128
#define NB    128
#define CSH   15                   // src chunk = 32768 rows (8MB window)
#define MAXNCH 8                   // max chunks
#define NKMAX  (MAXNCH * NB)       // max fine keys per bucket (1024)
#define CAP    4608                // sortfine ls2 capacity (mean 4092, +8 sigma)

typedef __attribute__((ext_vector_type(8))) short short8;
typedef __attribute__((ext_vector_type(4))) float float4v;

__device__ __forceinline__ unsigned short f2bf(float f) {   // RNE float->bf16
    unsigned u = __float_as_uint(f);
    unsigned r = 0x7fffu + ((u >> 16) & 1u);
    return (unsigned short)((u + r) >> 16);
}
__device__ __forceinline__ unsigned pk2(float a, float b) {
    return (unsigned)f2bf(a) | ((unsigned)f2bf(b) << 16);
}
// packed edge: bits[16:0]=src (N<2^17), bits[31:17]=fp16(w) sans sign (w>=0)
__device__ __forceinline__ unsigned enc_edge(int src, float w) {
    unsigned h = (unsigned)(__half_as_ushort(__float2half(w)) & 0x7FFF);
    return (h << 17) | (unsigned)src;
}
__device__ __forceinline__ void dec_edge(unsigned rec, int& s, float& w) {
    s = (int)(rec & 0x1FFFFu);
    __half hh;
    *(unsigned short*)&hh = (unsigned short)(rec >> 17);
    w = __half2float(hh);
}
__device__ __forceinline__ float bl(unsigned u) { return __uint_as_float(u << 16); }
__device__ __forceinline__ float bh(unsigned u) { return __uint_as_float(u & 0xffff0000u); }
__device__ __forceinline__ void fma8r(float (&a)[8], uint4 p, float w) {
    a[0] = fmaf(w, bl(p.x), a[0]); a[1] = fmaf(w, bh(p.x), a[1]);
    a[2] = fmaf(w, bl(p.y), a[2]); a[3] = fmaf(w, bh(p.y), a[3]);
    a[4] = fmaf(w, bl(p.z), a[4]); a[5] = fmaf(w, bh(p.z), a[5]);
    a[6] = fmaf(w, bl(p.w), a[6]); a[7] = fmaf(w, bh(p.w), a[7]);
}

// ---- W1^T bf16 precompute --------------------------------------------------
__global__ void k_wT(const float* __restrict__ W1, unsigned short* __restrict__ w1t) {
    int i = blockIdx.x * 256 + threadIdx.x;
    if (i >= HID_C * IN_C) return;
    int c = i >> 8, k = i & 255;
    w1t[i] = f2bf(W1[(size_t)k * HID_C + c]);
}

// ---- pass 1a: per-wg bucket histogram -> gcnt[b*W + w] (782 keys, cheap) ---
__global__ __launch_bounds__(256) void k_count(const int* __restrict__ ei,
                                               int* __restrict__ gcnt,
                                               int E, int K, int W, int CHv) {
    extern __shared__ int lh[];                // K ints (~3.1 KB)
    int w = blockIdx.x, t = threadIdx.x;
    for (int b = t; b < K; b += 256) lh[b] = 0;
    __syncthreads();
    int j0 = w * CHv;
    int j1 = min(j0 + CHv, E);
    for (int j = j0 + t; j < j1; j += 256)
        atomicAdd(&lh[ei[E + j] >> BSH], 1);
    __syncthreads();
    for (int b = t; b < K; b += 256) gcnt[(size_t)b * W + w] = lh[b];
}

// ---- scan: 4096 elems/block ------------------------------------------------
__global__ __launch_bounds__(256) void k_scanA4(const int* __restrict__ cnt,
                                                int* __restrict__ excl,
                                                int* __restrict__ bsum, int n) {
    __shared__ int ss[256];
    int t = threadIdx.x;
    int base = blockIdx.x * 4096 + t * 16;
    int v[16]; int s = 0;
#pragma unroll
    for (int q = 0; q < 16; q++) { v[q] = (base + q < n) ? cnt[base + q] : 0; s += v[q]; }
    ss[t] = s;
    __syncthreads();
    for (int d = 1; d < 256; d <<= 1) {
        int x = (t >= d) ? ss[t - d] : 0;
        __syncthreads();
        ss[t] += x;
        __syncthreads();
    }
    int pre = (t == 0) ? 0 : ss[t - 1];
    if (t == 255) bsum[blockIdx.x] = ss[255];
    int run = pre;
#pragma unroll
    for (int q = 0; q < 16; q++) { if (base + q < n) excl[base + q] = run; run += v[q]; }
}

__global__ __launch_bounds__(256) void k_scanB(int* __restrict__ bsum, int nb) {
    __shared__ int ss[256];
    int t = threadIdx.x;
    int v[8]; int s = 0;
#pragma unroll
    for (int q = 0; q < 8; q++) {
        int idx = t * 8 + q;
        v[q] = (idx < nb) ? bsum[idx] : 0; s += v[q];
    }
    ss[t] = s;
    __syncthreads();
    for (int d = 1; d < 256; d <<= 1) {
        int x = (t >= d) ? ss[t - d] : 0;
        __syncthreads();
        ss[t] += x;
        __syncthreads();
    }
    int run = (t == 0) ? 0 : ss[t - 1];
#pragma unroll
    for (int q = 0; q < 8; q++) {
        int idx = t * 8 + q;
        if (idx < nb) bsum[idx] = run;
        run += v[q];
    }
}

// ---- pass 1c: place edges into ebuf, bucket-grouped (inline bsum fixup) ----
__global__ __launch_bounds__(256) void k_place(const int* __restrict__ ei,
                                               const float* __restrict__ w,
                                               const int* __restrict__ gpos,
                                               const int* __restrict__ bsum,
                                               int2* __restrict__ ebuf,
                                               int E, int K, int W, int CHv) {
    extern __shared__ int lc[];                // K cursors
    int wg = blockIdx.x, t = threadIdx.x;
    for (int b = t; b < K; b += 256) {
        size_t i = (size_t)b * W + wg;
        lc[b] = gpos[i] + bsum[i >> 12];
    }
    __syncthreads();
    int j0 = wg * CHv;
    int j1 = min(j0 + CHv, E);
    for (int j = j0 + t; j < j1; j += 256) {
        int s = ei[j], d = ei[E + j];
        float wv = w[j];
        int pos = atomicAdd(&lc[d >> BSH], 1);
        ebuf[pos] = make_int2(s | ((d & (NB - 1)) << 17), __float_as_int(wv));
    }
}

// ---- fine sort: per bucket, sort by (src-chunk, dstloc); emit epack2 +
//      fine CSR rowfine + dinv. 29.2KB LDS -> 4 blocks/CU. ------------------
__global__ __launch_bounds__(512) void k_sortfine(const int* __restrict__ gcnt,
                                                  const int* __restrict__ bsum,
                                                  const int2* __restrict__ ebuf,
                                                  unsigned* __restrict__ epack2,
                                                  int* __restrict__ rowfine,
                                                  float* __restrict__ dinv,
                                                  int W, int NCH, int E, int K, int N) {
    __shared__ unsigned ls2[CAP];              // 18.4KB
    __shared__ int lh[NKMAX];                  // 4KB
    __shared__ int lc[NKMAX];                  // 4KB
    __shared__ int ss[512];                    // 2KB
    __shared__ float wsum[NB];                 // 0.5KB
    int b = blockIdx.x, t = threadIdx.x;
    size_t i0 = (size_t)b * W;
    int base = gcnt[i0] + bsum[i0 >> 12];
    int next;
    if (b + 1 < K) {
        size_t i1 = (size_t)(b + 1) * W;
        next = gcnt[i1] + bsum[i1 >> 12];
    } else next = E;
    int cnt = next - base;
    int nk = NCH << BSH;
    for (int i = t; i < nk; i += 512) lh[i] = 0;
    if (t < NB) wsum[t] = 1.0f;                // self-loop weight
    __syncthreads();
    for (int i = t; i < cnt; i += 512) {       // pass A: hist + weight sums
        int2 e = ebuf[base + i];
        int src = e.x & 0x1FFFF, dl = (e.x >> 17) & (NB - 1);
        atomicAdd(&lh[((src >> CSH) << BSH) + dl], 1);
        atomicAdd(&wsum[dl], __int_as_float(e.y));
    }
    __syncthreads();
    {   // exclusive scan of lh[0..nk) -> lc
        int v[4]; int s = 0;
#pragma unroll
        for (int q = 0; q < 4; q++) {
            int idx = t * 4 + q;
            v[q] = (idx < nk) ? lh[idx] : 0; s += v[q];
        }
        ss[t] = s;
        __syncthreads();
        for (int d = 1; d < 512; d <<= 1) {
            int x = (t >= d) ? ss[t - d] : 0;
            __syncthreads();
            ss[t] += x;
            __syncthreads();
        }
        int run = (t == 0) ? 0 : ss[t - 1];
#pragma unroll
        for (int q = 0; q < 4; q++) {
            int idx = t * 4 + q;
            if (idx < nk) lc[idx] = run;
            run += v[q];
        }
    }
    __syncthreads();
    for (int i = t; i < nk; i += 512)          // fine CSR (before cursors move)
        rowfine[(size_t)b * nk + i] = base + lc[i];
    __syncthreads();
    bool fits = cnt <= CAP;
    if (fits) {
        for (int i = t; i < cnt; i += 512) {   // pass B: scatter (ebuf L2-hot)
            int2 e = ebuf[base + i];
            int src = e.x & 0x1FFFF, dl = (e.x >> 17) & (NB - 1);
            int pos = atomicAdd(&lc[((src >> CSH) << BSH) + dl], 1);
            ls2[pos] = enc_edge(src, __int_as_float(e.y));
        }
        __syncthreads();
        for (int i = t; i < cnt; i += 512)     // coalesced 4B out
            epack2[base + i] = ls2[i];
    } else {                                   // overflow fallback (rare)
        for (int i = t; i < cnt; i += 512) {
            int2 e = ebuf[base + i];
            int src = e.x & 0x1FFFF, dl = (e.x >> 17) & (NB - 1);
            int pos = atomicAdd(&lc[((src >> CSH) << BSH) + dl], 1);
            epack2[base + pos] = enc_edge(src, __int_as_float(e.y));
        }
    }
    if (t < NB) {
        int node = (b << BSH) + t;
        if (node < N) dinv[node] = rsqrtf(wsum[t]);
    }
    if (b == 0 && t == 0) rowfine[(size_t)K * nk] = E;   // sentinel
}

// ---- GEMM1 (MFMA bf16): h1b[N,128] = dinv[.] * (x[N,256] @ W1) -------------
#define XS_LD 36
#define WT2_LD 132
__global__ __launch_bounds__(256) void k_gemm1(const float* __restrict__ x,
                                               const unsigned short* __restrict__ w1t,
                                               const float* __restrict__ dinv,
                                               unsigned short* __restrict__ h1b, int n) {
    __shared__ __align__(16) unsigned short wt[HID_C * WT2_LD];   // 33.8KB
    __shared__ __align__(16) unsigned short xs[64 * XS_LD];       // 4.6KB
    int tid  = threadIdx.x;
    int row0 = blockIdx.x * 64;
    int wv = tid >> 6, ln = tid & 63;
    int m = ln & 15, quad = ln >> 4;
    float4v acc[8];
#pragma unroll
    for (int ct = 0; ct < 8; ct++) acc[ct] = (float4v){0.f, 0.f, 0.f, 0.f};

    for (int p = 0; p < 2; p++) {
        __syncthreads();                       // prev-half wt readers done
        for (int it = 0; it < 8; it++) {       // stage 32KB half of w1t
            int idx = it * 256 + tid;
            int c = idx >> 4, kc = idx & 15;
            const unsigned short* src = w1t + (size_t)c * IN_C + (p << 7) + kc * 8;
            uint2 a = *(const uint2*)(src);
            uint2 b = *(const uint2*)(src + 4);
            *(uint2*)(wt + c * WT2_LD + kc * 8)     = a;
            *(uint2*)(wt + c * WT2_LD + kc * 8 + 4) = b;
        }
        for (int kk = 0; kk < 4; kk++) {
            int k0 = (p << 7) + kk * 32;
            __syncthreads();                   // wt staged / xs readers done
            {
                int r = tid >> 2, s4 = tid & 3;
                int gr = row0 + r; if (gr >= n) gr = n - 1;
                const float4* px = (const float4*)(x + (size_t)gr * IN_C + k0 + s4 * 8);
                float4 a = px[0], bq = px[1];
                uint2* dxs = (uint2*)(xs + r * XS_LD + s4 * 8);
                dxs[0] = make_uint2(pk2(a.x, a.y), pk2(a.z, a.w));
                dxs[1] = make_uint2(pk2(bq.x, bq.y), pk2(bq.z, bq.w));
            }
            __syncthreads();
            union { uint2 u[2]; short8 v; } af;
            const uint2* pa = (const uint2*)(xs + (wv * 16 + m) * XS_LD + quad * 8);
            af.u[0] = pa[0]; af.u[1] = pa[1];
#pragma unroll
            for (int ct = 0; ct < 8; ct++) {
                union { uint2 u[2]; short8 v; } bf;
                const uint2* pb = (const uint2*)(wt + (ct * 16 + m) * WT2_LD + kk * 32 + quad * 8);
                bf.u[0] = pb[0]; bf.u[1] = pb[1];
                acc[ct] = __builtin_amdgcn_mfma_f32_16x16x32_bf16(af.v, bf.v, acc[ct], 0, 0, 0);
            }
        }
    }
    __syncthreads();                           // wt readers done; reuse as ot
    float4 dv = *(const float4*)(dinv + row0 + wv * 16 + quad * 4);
    const float* dvf = (const float*)&dv;
    unsigned short* ot = wt;                   // 64*136*2 = 17.4KB <= 33.8KB
#pragma unroll
    for (int ct = 0; ct < 8; ct++)
#pragma unroll
        for (int r = 0; r < 4; r++)
            ot[(wv * 16 + quad * 4 + r) * 136 + ct * 16 + m] = f2bf(acc[ct][r] * dvf[r]);
    __syncthreads();
#pragma unroll
    for (int p4 = 0; p4 < 4; p4++) {
        int idx = p4 * 256 + tid;
        int r = idx >> 4, c8 = idx & 15;
        if (row0 + r < n)
            *(uint4*)(h1b + (size_t)(row0 + r) * HID_C + c8 * 8) =
                *(const uint4*)(ot + r * 136 + c8 * 8);
    }
}

// ---- layer-1 aggregation + fused gemm2: chunk-outer, dual-run 8-deep -------
// Quad processes its TWO dst-runs (u=0,1) concurrently: 8 independent uint4
// gathers issued back-to-back per iteration (2x the in-flight bytes of R10,
// which the compiler had serialized at VGPR=32). Iterations per wave =
// ceil(max(nA,nB)/4) instead of sum. CSH=15: runs avg 9.2 -> less clamp
// waste, half the chunk-loop setups.
__global__ __launch_bounds__(512, 4) void k_agg1(const int* __restrict__ rowfine,
                                                 const unsigned* __restrict__ epack2,
                                                 const unsigned short* __restrict__ h1b,
                                                 const float* __restrict__ dinv,
                                                 const float* __restrict__ b1,
                                                 const float* __restrict__ W2,
                                                 float* __restrict__ h2,
                                                 int NCH, int K, int N) {
    int blk = blockIdx.x;
    int b = blk >> 1, half = blk & 1;
    int t = threadIdx.x;
    int wv = t >> 6, lane = t & 63;
    int g = lane >> 4, c16 = lane & 15;
    int nk = NCH << BSH;
    const int* rfb = rowfine + (size_t)b * nk;
    const unsigned short* hb = h1b + c16 * 8;  // lane-fixed column offset
    int dbase = (half << 6) + (wv << 3);
    float au[2][8];
#pragma unroll
    for (int u = 0; u < 2; u++)
#pragma unroll
        for (int k = 0; k < 8; k++) au[u][k] = 0.f;

    for (int ch = 0; ch < NCH; ch++) {         // chunk = outermost time axis
        const int* rf = rfb + (ch << BSH);
        int d0 = dbase + g, d1 = dbase + 4 + g;
        int jb0 = rf[d0], je0 = rf[d0 + 1];
        int jb1 = rf[d1], je1 = rf[d1 + 1];
        int l0 = max(je0 - 1, 0), l1 = max(je1 - 1, 0);
        int nmax = max(je0 - jb0, je1 - jb1);
        for (int k = 0; k < nmax; k += 4) {
            int j0 = jb0 + k, j1 = jb1 + k;
            int a0 = min(j0,     l0), a1 = min(j0 + 1, l0);
            int a2 = min(j0 + 2, l0), a3 = min(j0 + 3, l0);
            int b0 = min(j1,     l1), b1 = min(j1 + 1, l1);
            int b2 = min(j1 + 2, l1), b3 = min(j1 + 3, l1);
            unsigned ra0 = epack2[a0], ra1 = epack2[a1];
            unsigned ra2 = epack2[a2], ra3 = epack2[a3];
            unsigned rb0 = epack2[b0], rb1 = epack2[b1];
            unsigned rb2 = epack2[b2], rb3 = epack2[b3];
            int sa0, sa1, sa2, sa3, sb0, sb1, sb2, sb3;
            float wa0, wa1, wa2, wa3, wb0, wb1, wb2, wb3;
            dec_edge(ra0, sa0, wa0); dec_edge(ra1, sa1, wa1);
            dec_edge(ra2, sa2, wa2); dec_edge(ra3, sa3, wa3);
            dec_edge(rb0, sb0, wb0); dec_edge(rb1, sb1, wb1);
            dec_edge(rb2, sb2, wb2); dec_edge(rb3, sb3, wb3);
            wa0 = (j0     < je0) ? wa0 : 0.f;
            wa1 = (j0 + 1 < je0) ? wa1 : 0.f;
            wa2 = (j0 + 2 < je0) ? wa2 : 0.f;
            wa3 = (j0 + 3 < je0) ? wa3 : 0.f;
            wb0 = (j1     < je1) ? wb0 : 0.f;
            wb1 = (j1 + 1 < je1) ? wb1 : 0.f;
            wb2 = (j1 + 2 < je1) ? wb2 : 0.f;
            wb3 = (j1 + 3 < je1) ? wb3 : 0.f;
            uint4 pa0 = *(const uint4*)(hb + ((size_t)sa0 << 7));
            uint4 pa1 = *(const uint4*)(hb + ((size_t)sa1 << 7));
            uint4 pa2 = *(const uint4*)(hb + ((size_t)sa2 << 7));
            uint4 pa3 = *(const uint4*)(hb + ((size_t)sa3 << 7));
            uint4 pb0 = *(const uint4*)(hb + ((size_t)sb0 << 7));
            uint4 pb1 = *(const uint4*)(hb + ((size_t)sb1 << 7));
            uint4 pb2 = *(const uint4*)(hb + ((size_t)sb2 << 7));
            uint4 pb3 = *(const uint4*)(hb + ((size_t)sb3 << 7));
            fma8r(au[0], pa0, wa0);
            fma8r(au[0], pa1, wa1);
            fma8r(au[0], pa2, wa2);
            fma8r(au[0], pa3, wa3);
            fma8r(au[1], pb0, wb0);
            fma8r(au[1], pb1, wb1);
            fma8r(au[1], pb2, wb2);
            fma8r(au[1], pb3, wb3);
        }
    }
    // epilogue: +self, *dinv, +b1, relu, W2 dot, quad butterfly -> h2'
    float4 b1a = *(const float4*)(b1 + c16 * 8);
    float4 b1b = *(const float4*)(b1 + c16 * 8 + 4);
    const float4* wp = (const float4*)(W2 + c16 * 16);
    float4 w0 = wp[0], w1 = wp[1], w2 = wp[2], w3 = wp[3];
#pragma unroll
    for (int u = 0; u < 2; u++) {
        int d = dbase + u * 4 + g;
        int node = (b << BSH) + d;
        bool valid = node < N;
        float di = valid ? dinv[node] : 0.f;
        uint4 sp = make_uint4(0, 0, 0, 0);
        if (valid) sp = *(const uint4*)(h1b + ((size_t)node << 7) + c16 * 8);
        float e0 = fmaxf(fmaf(di, au[u][0] + bl(sp.x), b1a.x), 0.f);
        float e1 = fmaxf(fmaf(di, au[u][1] + bh(sp.x), b1a.y), 0.f);
        float e2 = fmaxf(fmaf(di, au[u][2] + bl(sp.y), b1a.z), 0.f);
        float e3 = fmaxf(fmaf(di, au[u][3] + bh(sp.y), b1a.w), 0.f);
        float e4 = fmaxf(fmaf(di, au[u][4] + bl(sp.z), b1b.x), 0.f);
        float e5 = fmaxf(fmaf(di, au[u][5] + bh(sp.z), b1b.y), 0.f);
        float e6 = fmaxf(fmaf(di, au[u][6] + bl(sp.w), b1b.z), 0.f);
        float e7 = fmaxf(fmaf(di, au[u][7] + bh(sp.w), b1b.w), 0.f);
        float s0 = e0 * w0.x + e1 * w0.z + e2 * w1.x + e3 * w1.z
                 + e4 * w2.x + e5 * w2.z + e6 * w3.x + e7 * w3.z;
        float s1 = e0 * w0.y + e1 * w0.w + e2 * w1.y + e3 * w1.w
                 + e4 * w2.y + e5 * w2.w + e6 * w3.y + e7 * w3.w;
#pragma unroll
        for (int dd = 1; dd < 16; dd <<= 1) {
            s0 += __shfl_xor(s0, dd);
            s1 += __shfl_xor(s1, dd);
        }
        if (c16 == 0 && valid)
            ((float2*)h2)[node] = make_float2(di * s0, di * s1);
    }
}

// ---- layer-2 aggregation: fine-CSR walk, 2 lanes/dst, 4-deep unroll --------
__global__ __launch_bounds__(256) void k_agg2(const int* __restrict__ rowfine,
                                              const unsigned* __restrict__ epack2,
                                              const float* __restrict__ h2,
                                              const float* __restrict__ dinv,
                                              const float* __restrict__ b2,
                                              float* __restrict__ out,
                                              int NCH, int K, int N) {
    __shared__ float a2[NB * 2];
    int b = blockIdx.x, t = threadIdx.x;
    int d = t & 127, half = t >> 7;
    int nk = NCH << BSH;
    const int* rfb = rowfine + (size_t)b * nk;
    float sx = 0.f, sy = 0.f;
    for (int ch = half; ch < NCH; ch += 2) {
        int jb = rfb[(ch << BSH) + d];
        int je = rfb[(ch << BSH) + d + 1];
        for (int j = jb; j < je; j += 4) {     // 4 gathers in flight
            int j1 = min(j + 1, je - 1);
            int j2 = min(j + 2, je - 1);
            int j3 = min(j + 3, je - 1);
            unsigned r0 = epack2[j],  r1 = epack2[j1];
            unsigned r2 = epack2[j2], r3 = epack2[j3];
            int s0, s1, s2, s3; float w0, w1, w2, w3;
            dec_edge(r0, s0, w0); dec_edge(r1, s1, w1);
            dec_edge(r2, s2, w2); dec_edge(r3, s3, w3);
            w1 = (j + 1 < je) ? w1 : 0.f;
            w2 = (j + 2 < je) ? w2 : 0.f;
            w3 = (j + 3 < je) ? w3 : 0.f;
            float2 v0 = ((const float2*)h2)[s0];
            float2 v1 = ((const float2*)h2)[s1];
            float2 v2 = ((const float2*)h2)[s2];
            float2 v3 = ((const float2*)h2)[s3];
            sx = fmaf(w0, v0.x, sx); sy = fmaf(w0, v0.y, sy);
            sx = fmaf(w1, v1.x, sx); sy = fmaf(w1, v1.y, sy);
            sx = fmaf(w2, v2.x, sx); sy = fmaf(w2, v2.y, sy);
            sx = fmaf(w3, v3.x, sx); sy = fmaf(w3, v3.y, sy);
        }
    }
    if (half == 1) { a2[d * 2] = sx; a2[d * 2 + 1] = sy; }
    __syncthreads();
    if (half == 0) {
        int node = (b << BSH) + d;
        if (node < N) {
            float di = dinv[node];
            float2 hv = ((const float2*)h2)[node];   // already dinv*H2
            sx += a2[d * 2]; sy += a2[d * 2 + 1];
            ((float2*)out)[node] = make_float2(b2[0] + di * (sx + hv.x),
                                               b2[1] + di * (sy + hv.y));
        }
    }
}

static inline size_t algn16(size_t v) { return (v + 15) & ~(size_t)15; }

extern "C" void kernel_launch(void* const* d_in, const int* in_sizes, int n_in,
                              void* d_out, int out_size, void* d_ws, size_t ws_size,
                              hipStream_t stream) {
    const float* x  = (const float*)d_in[0];
    const int*   ei = (const int*)d_in[1];   // [2,E] int32
    const float* ew = (const float*)d_in[2];
    const float* W1 = (const float*)d_in[3];
    const float* b1 = (const float*)d_in[4];
    const float* W2 = (const float*)d_in[5];
    const float* b2 = (const float*)d_in[6];
    float* out = (float*)d_out;

    int N = in_sizes[0] / IN_C;
    int E = in_sizes[2];
    int K = (N + NB - 1) >> BSH;             // buckets (782)
    int NCH = (N + (1 << CSH) - 1) >> CSH;   // src chunks (4)
    int nk = NCH << BSH;                     // fine keys per bucket (512)
    int W = 512;                             // pass-1 workgroups (2/CU)
    int CHv = (E + W - 1) / W;
    int KW = K * W;                          // coarse hist size (~400k)

    char* ws = (char*)d_ws;
    float* dinv    = (float*)ws; ws += algn16((size_t)N * 4);
    int*   gcnt    = (int*)ws;   ws += algn16((size_t)KW * 4);
    int*   bsum    = (int*)ws;   ws += 8192;
    int*   rowfine = (int*)ws;   ws += algn16(((size_t)K * nk + 1) * 4);
    unsigned* epack2 = (unsigned*)ws; ws += algn16((size_t)E * 4);
    // ebuf (E*8) and h1b (N*256) alias: sortfine consumes ebuf before gemm1
    size_t big = (size_t)E * 8;
    size_t h1sz = (size_t)N * HID_C * 2;
    if (h1sz > big) big = h1sz;
    int2* ebuf = (int2*)ws;
    unsigned short* h1b = (unsigned short*)ws; ws += algn16(big);
    unsigned short* w1t = (unsigned short*)ws; ws += algn16((size_t)HID_C * IN_C * 2);
    float* h2      = (float*)ws; ws += algn16((size_t)N * OUT_C * 4);

    int nb_s4 = (KW + 4095) / 4096;          // ~98 (<=2048 for k_scanB)
    size_t lds_k = (size_t)K * 4;            // ~3.1 KB dynamic LDS

    k_wT      <<<(HID_C * IN_C + 255) / 256, 256, 0, stream>>>(W1, w1t);
    k_count   <<<W, 256, lds_k, stream>>>(ei, gcnt, E, K, W, CHv);
    k_scanA4  <<<nb_s4, 256, 0, stream>>>(gcnt, gcnt, bsum, KW);
    k_scanB   <<<1, 256, 0, stream>>>(bsum, nb_s4);
    k_place   <<<W, 256, lds_k, stream>>>(ei, ew, gcnt, bsum, ebuf, E, K, W, CHv);
    k_sortfine<<<K, 512, 0, stream>>>(gcnt, bsum, ebuf, epack2, rowfine, dinv, W, NCH, E, K, N);
    k_gemm1   <<<(N + 63) / 64, 256, 0, stream>>>(x, w1t, dinv, h1b, N);
    k_agg1    <<<K * 2, 512, 0, stream>>>(rowfine, epack2, h1b, dinv, b1, W2, h2, NCH, K, N);
    k_agg2    <<<K, 256, 0, stream>>>(rowfine, epack2, h2, dinv, b2, out, NCH, K, N);
}

// Round 12
// 457.838 us; speedup vs baseline: 1.0349x; 1.0349x over previous
//
#include <hip/hip_runtime.h>
#include <hip/hip_fp16.h>

#define IN_C  256
#define HID_C 128
#define OUT_C 2
#define BSH   7                    // nodes per bucket = 128
#define NB    128
#define CSH   14                   // src chunk = 16384 rows (4MB L2 window)
#define MAXNCH 8                   // max chunks
#define NKMAX  (MAXNCH * NB)       // max fine keys per bucket (1024)
#define CAP    4608                // sortfine ls2 capacity (mean 4092, +8 sigma)

typedef __attribute__((ext_vector_type(8))) short short8;
typedef __attribute__((ext_vector_type(4))) float float4v;

__device__ __forceinline__ unsigned short f2bf(float f) {   // RNE float->bf16
    unsigned u = __float_as_uint(f);
    unsigned r = 0x7fffu + ((u >> 16) & 1u);
    return (unsigned short)((u + r) >> 16);
}
__device__ __forceinline__ unsigned pk2(float a, float b) {
    return (unsigned)f2bf(a) | ((unsigned)f2bf(b) << 16);
}
// packed edge: bits[16:0]=src (N<2^17), bits[31:17]=fp16(w) sans sign (w>=0)
__device__ __forceinline__ unsigned enc_edge(int src, float w) {
    unsigned h = (unsigned)(__half_as_ushort(__float2half(w)) & 0x7FFF);
    return (h << 17) | (unsigned)src;
}
__device__ __forceinline__ void dec_edge(unsigned rec, int& s, float& w) {
    s = (int)(rec & 0x1FFFFu);
    __half hh;
    *(unsigned short*)&hh = (unsigned short)(rec >> 17);
    w = __half2float(hh);
}
__device__ __forceinline__ float bl(unsigned u) { return __uint_as_float(u << 16); }
__device__ __forceinline__ float bh(unsigned u) { return __uint_as_float(u & 0xffff0000u); }
__device__ __forceinline__ void fma8r(float (&a)[8], uint4 p, float w) {
    a[0] = fmaf(w, bl(p.x), a[0]); a[1] = fmaf(w, bh(p.x), a[1]);
    a[2] = fmaf(w, bl(p.y), a[2]); a[3] = fmaf(w, bh(p.y), a[3]);
    a[4] = fmaf(w, bl(p.z), a[4]); a[5] = fmaf(w, bh(p.z), a[5]);
    a[6] = fmaf(w, bl(p.w), a[6]); a[7] = fmaf(w, bh(p.w), a[7]);
}

// ---- W1^T bf16 precompute --------------------------------------------------
__global__ void k_wT(const float* __restrict__ W1, unsigned short* __restrict__ w1t) {
    int i = blockIdx.x * 256 + threadIdx.x;
    if (i >= HID_C * IN_C) return;
    int c = i >> 8, k = i & 255;
    w1t[i] = f2bf(W1[(size_t)k * HID_C + c]);
}

// ---- pass 1a: per-wg bucket histogram -> gcnt[b*W + w] (782 keys, cheap) ---
__global__ __launch_bounds__(256) void k_count(const int* __restrict__ ei,
                                               int* __restrict__ gcnt,
                                               int E, int K, int W, int CHv) {
    extern __shared__ int lh[];                // K ints (~3.1 KB)
    int w = blockIdx.x, t = threadIdx.x;
    for (int b = t; b < K; b += 256) lh[b] = 0;
    __syncthreads();
    int j0 = w * CHv;
    int j1 = min(j0 + CHv, E);
    for (int j = j0 + t; j < j1; j += 256)
        atomicAdd(&lh[ei[E + j] >> BSH], 1);
    __syncthreads();
    for (int b = t; b < K; b += 256) gcnt[(size_t)b * W + w] = lh[b];
}

// ---- scan: 4096 elems/block ------------------------------------------------
__global__ __launch_bounds__(256) void k_scanA4(const int* __restrict__ cnt,
                                                int* __restrict__ excl,
                                                int* __restrict__ bsum, int n) {
    __shared__ int ss[256];
    int t = threadIdx.x;
    int base = blockIdx.x * 4096 + t * 16;
    int v[16]; int s = 0;
#pragma unroll
    for (int q = 0; q < 16; q++) { v[q] = (base + q < n) ? cnt[base + q] : 0; s += v[q]; }
    ss[t] = s;
    __syncthreads();
    for (int d = 1; d < 256; d <<= 1) {
        int x = (t >= d) ? ss[t - d] : 0;
        __syncthreads();
        ss[t] += x;
        __syncthreads();
    }
    int pre = (t == 0) ? 0 : ss[t - 1];
    if (t == 255) bsum[blockIdx.x] = ss[255];
    int run = pre;
#pragma unroll
    for (int q = 0; q < 16; q++) { if (base + q < n) excl[base + q] = run; run += v[q]; }
}

__global__ __launch_bounds__(256) void k_scanB(int* __restrict__ bsum, int nb) {
    __shared__ int ss[256];
    int t = threadIdx.x;
    int v[8]; int s = 0;
#pragma unroll
    for (int q = 0; q < 8; q++) {
        int idx = t * 8 + q;
        v[q] = (idx < nb) ? bsum[idx] : 0; s += v[q];
    }
    ss[t] = s;
    __syncthreads();
    for (int d = 1; d < 256; d <<= 1) {
        int x = (t >= d) ? ss[t - d] : 0;
        __syncthreads();
        ss[t] += x;
        __syncthreads();
    }
    int run = (t == 0) ? 0 : ss[t - 1];
#pragma unroll
    for (int q = 0; q < 8; q++) {
        int idx = t * 8 + q;
        if (idx < nb) bsum[idx] = run;
        run += v[q];
    }
}

// ---- pass 1c: place edges into ebuf, bucket-grouped (inline bsum fixup) ----
__global__ __launch_bounds__(256) void k_place(const int* __restrict__ ei,
                                               const float* __restrict__ w,
                                               const int* __restrict__ gpos,
                                               const int* __restrict__ bsum,
                                               int2* __restrict__ ebuf,
                                               int E, int K, int W, int CHv) {
    extern __shared__ int lc[];                // K cursors
    int wg = blockIdx.x, t = threadIdx.x;
    for (int b = t; b < K; b += 256) {
        size_t i = (size_t)b * W + wg;
        lc[b] = gpos[i] + bsum[i >> 12];
    }
    __syncthreads();
    int j0 = wg * CHv;
    int j1 = min(j0 + CHv, E);
    for (int j = j0 + t; j < j1; j += 256) {
        int s = ei[j], d = ei[E + j];
        float wv = w[j];
        int pos = atomicAdd(&lc[d >> BSH], 1);
        ebuf[pos] = make_int2(s | ((d & (NB - 1)) << 17), __float_as_int(wv));
    }
}

// ---- fine sort: per bucket, sort by (src-chunk, dstloc); emit epack2 +
//      fine CSR rowfine + dinv. 29.2KB LDS -> 4 blocks/CU. ------------------
__global__ __launch_bounds__(512) void k_sortfine(const int* __restrict__ gcnt,
                                                  const int* __restrict__ bsum,
                                                  const int2* __restrict__ ebuf,
                                                  unsigned* __restrict__ epack2,
                                                  int* __restrict__ rowfine,
                                                  float* __restrict__ dinv,
                                                  int W, int NCH, int E, int K, int N) {
    __shared__ unsigned ls2[CAP];              // 18.4KB
    __shared__ int lh[NKMAX];                  // 4KB
    __shared__ int lc[NKMAX];                  // 4KB
    __shared__ int ss[512];                    // 2KB
    __shared__ float wsum[NB];                 // 0.5KB
    int b = blockIdx.x, t = threadIdx.x;
    size_t i0 = (size_t)b * W;
    int base = gcnt[i0] + bsum[i0 >> 12];
    int next;
    if (b + 1 < K) {
        size_t i1 = (size_t)(b + 1) * W;
        next = gcnt[i1] + bsum[i1 >> 12];
    } else next = E;
    int cnt = next - base;
    int nk = NCH << BSH;
    for (int i = t; i < nk; i += 512) lh[i] = 0;
    if (t < NB) wsum[t] = 1.0f;                // self-loop weight
    __syncthreads();
    for (int i = t; i < cnt; i += 512) {       // pass A: hist + weight sums
        int2 e = ebuf[base + i];
        int src = e.x & 0x1FFFF, dl = (e.x >> 17) & (NB - 1);
        atomicAdd(&lh[((src >> CSH) << BSH) + dl], 1);
        atomicAdd(&wsum[dl], __int_as_float(e.y));
    }
    __syncthreads();
    {   // exclusive scan of lh[0..nk) -> lc
        int v[4]; int s = 0;
#pragma unroll
        for (int q = 0; q < 4; q++) {
            int idx = t * 4 + q;
            v[q] = (idx < nk) ? lh[idx] : 0; s += v[q];
        }
        ss[t] = s;
        __syncthreads();
        for (int d = 1; d < 512; d <<= 1) {
            int x = (t >= d) ? ss[t - d] : 0;
            __syncthreads();
            ss[t] += x;
            __syncthreads();
        }
        int run = (t == 0) ? 0 : ss[t - 1];
#pragma unroll
        for (int q = 0; q < 4; q++) {
            int idx = t * 4 + q;
            if (idx < nk) lc[idx] = run;
            run += v[q];
        }
    }
    __syncthreads();
    for (int i = t; i < nk; i += 512)          // fine CSR (before cursors move)
        rowfine[(size_t)b * nk + i] = base + lc[i];
    __syncthreads();
    bool fits = cnt <= CAP;
    if (fits) {
        for (int i = t; i < cnt; i += 512) {   // pass B: scatter (ebuf L2-hot)
            int2 e = ebuf[base + i];
            int src = e.x & 0x1FFFF, dl = (e.x >> 17) & (NB - 1);
            int pos = atomicAdd(&lc[((src >> CSH) << BSH) + dl], 1);
            ls2[pos] = enc_edge(src, __int_as_float(e.y));
        }
        __syncthreads();
        for (int i = t; i < cnt; i += 512)     // coalesced 4B out
            epack2[base + i] = ls2[i];
    } else {                                   // overflow fallback (rare)
        for (int i = t; i < cnt; i += 512) {
            int2 e = ebuf[base + i];
            int src = e.x & 0x1FFFF, dl = (e.x >> 17) & (NB - 1);
            int pos = atomicAdd(&lc[((src >> CSH) << BSH) + dl], 1);
            epack2[base + pos] = enc_edge(src, __int_as_float(e.y));
        }
    }
    if (t < NB) {
        int node = (b << BSH) + t;
        if (node < N) dinv[node] = rsqrtf(wsum[t]);
    }
    if (b == 0 && t == 0) rowfine[(size_t)K * nk] = E;   // sentinel
}

// ---- GEMM1 (MFMA bf16): h1b[N,128] = dinv[.] * (x[N,256] @ W1) -------------
// 128 rows/block (grid 782): W-staging traffic + barriers per row halved vs
// 64-row version. LDS = wt 33.8KB + xs 9.2KB = 43KB (3 blocks/CU); epilogue
// ot (128 x 132 ushort = 33.8KB) aliases wt exactly.
#define XS_LD 36
#define WT2_LD 132
__global__ __launch_bounds__(256) void k_gemm1(const float* __restrict__ x,
                                               const unsigned short* __restrict__ w1t,
                                               const float* __restrict__ dinv,
                                               unsigned short* __restrict__ h1b, int n) {
    __shared__ __align__(16) unsigned short wt[HID_C * WT2_LD];   // 33.8KB
    __shared__ __align__(16) unsigned short xs[128 * XS_LD];      // 9.2KB
    int tid  = threadIdx.x;
    int row0 = blockIdx.x * 128;
    int wv = tid >> 6, ln = tid & 63;
    int m = ln & 15, quad = ln >> 4;
    float4v acc[2][8];
#pragma unroll
    for (int rt = 0; rt < 2; rt++)
#pragma unroll
        for (int ct = 0; ct < 8; ct++) acc[rt][ct] = (float4v){0.f, 0.f, 0.f, 0.f};

    for (int p = 0; p < 2; p++) {
        __syncthreads();                       // prev-half wt readers done
        for (int it = 0; it < 8; it++) {       // stage 32KB half of w1t
            int idx = it * 256 + tid;
            int c = idx >> 4, kc = idx & 15;
            const unsigned short* src = w1t + (size_t)c * IN_C + (p << 7) + kc * 8;
            uint2 a = *(const uint2*)(src);
            uint2 b = *(const uint2*)(src + 4);
            *(uint2*)(wt + c * WT2_LD + kc * 8)     = a;
            *(uint2*)(wt + c * WT2_LD + kc * 8 + 4) = b;
        }
        for (int kk = 0; kk < 4; kk++) {
            int k0 = (p << 7) + kk * 32;
            __syncthreads();                   // wt staged / xs readers done
#pragma unroll
            for (int rr = 0; rr < 2; rr++) {   // stage 128 rows x 32 cols of x
                int r = rr * 64 + (tid >> 2), s4 = tid & 3;
                int gr = row0 + r; if (gr >= n) gr = n - 1;
                const float4* px = (const float4*)(x + (size_t)gr * IN_C + k0 + s4 * 8);
                float4 a = px[0], bq = px[1];
                uint2* dxs = (uint2*)(xs + r * XS_LD + s4 * 8);
                dxs[0] = make_uint2(pk2(a.x, a.y), pk2(a.z, a.w));
                dxs[1] = make_uint2(pk2(bq.x, bq.y), pk2(bq.z, bq.w));
            }
            __syncthreads();
            union { uint2 u[2]; short8 v; } af0, af1;
            const uint2* pa0 = (const uint2*)(xs + (wv * 16 + m) * XS_LD + quad * 8);
            const uint2* pa1 = (const uint2*)(xs + (64 + wv * 16 + m) * XS_LD + quad * 8);
            af0.u[0] = pa0[0]; af0.u[1] = pa0[1];
            af1.u[0] = pa1[0]; af1.u[1] = pa1[1];
#pragma unroll
            for (int ct = 0; ct < 8; ct++) {
                union { uint2 u[2]; short8 v; } bf;
                const uint2* pb = (const uint2*)(wt + (ct * 16 + m) * WT2_LD + kk * 32 + quad * 8);
                bf.u[0] = pb[0]; bf.u[1] = pb[1];
                acc[0][ct] = __builtin_amdgcn_mfma_f32_16x16x32_bf16(af0.v, bf.v, acc[0][ct], 0, 0, 0);
                acc[1][ct] = __builtin_amdgcn_mfma_f32_16x16x32_bf16(af1.v, bf.v, acc[1][ct], 0, 0, 0);
            }
        }
    }
    __syncthreads();                           // wt readers done; reuse as ot
    unsigned short* ot = wt;                   // 128*132*2 = 33.8KB = wt
#pragma unroll
    for (int rt = 0; rt < 2; rt++) {
        float4 dv = *(const float4*)(dinv + row0 + rt * 64 + wv * 16 + quad * 4);
        const float* dvf = (const float*)&dv;
#pragma unroll
        for (int ct = 0; ct < 8; ct++)
#pragma unroll
            for (int r = 0; r < 4; r++)
                ot[(rt * 64 + wv * 16 + quad * 4 + r) * WT2_LD + ct * 16 + m] =
                    f2bf(acc[rt][ct][r] * dvf[r]);
    }
    __syncthreads();
#pragma unroll
    for (int p4 = 0; p4 < 8; p4++) {
        int idx = p4 * 256 + tid;
        int r = idx >> 4, c8 = idx & 15;
        if (row0 + r < n)
            *(uint4*)(h1b + (size_t)(row0 + r) * HID_C + c8 * 8) =
                *(const uint4*)(ot + r * WT2_LD + c8 * 8);
    }
}

// ---- layer-1 aggregation + fused gemm2: chunk-outer walk, split buckets ----
// R10 exact form: sequential u-loop, 4 edges in flight/quad, CSH=14.
__global__ __launch_bounds__(512, 4) void k_agg1(const int* __restrict__ rowfine,
                                                 const unsigned* __restrict__ epack2,
                                                 const unsigned short* __restrict__ h1b,
                                                 const float* __restrict__ dinv,
                                                 const float* __restrict__ b1,
                                                 const float* __restrict__ W2,
                                                 float* __restrict__ h2,
                                                 int NCH, int K, int N) {
    int blk = blockIdx.x;
    int b = blk >> 1, half = blk & 1;
    int t = threadIdx.x;
    int wv = t >> 6, lane = t & 63;
    int g = lane >> 4, c16 = lane & 15;
    int nk = NCH << BSH;
    const int* rfb = rowfine + (size_t)b * nk;
    const unsigned short* hb = h1b + c16 * 8;  // lane-fixed column offset
    int dbase = (half << 6) + (wv << 3);
    float au[2][8];
#pragma unroll
    for (int u = 0; u < 2; u++)
#pragma unroll
        for (int k = 0; k < 8; k++) au[u][k] = 0.f;

    for (int ch = 0; ch < NCH; ch++) {         // chunk = outermost time axis
        const int* rf = rfb + (ch << BSH);
#pragma unroll
        for (int u = 0; u < 2; u++) {
            int d = dbase + u * 4 + g;
            int jb = rf[d], je = rf[d + 1];
            for (int j = jb; j < je; j += 4) { // 4 edges in flight per quad
                int j1 = min(j + 1, je - 1);
                int j2 = min(j + 2, je - 1);
                int j3 = min(j + 3, je - 1);
                unsigned r0 = epack2[j],  r1 = epack2[j1];
                unsigned r2 = epack2[j2], r3 = epack2[j3];
                int s0, s1, s2, s3; float w0, w1, w2, w3;
                dec_edge(r0, s0, w0); dec_edge(r1, s1, w1);
                dec_edge(r2, s2, w2); dec_edge(r3, s3, w3);
                w1 = (j + 1 < je) ? w1 : 0.f;
                w2 = (j + 2 < je) ? w2 : 0.f;
                w3 = (j + 3 < je) ? w3 : 0.f;
                uint4 p0 = *(const uint4*)(hb + ((size_t)s0 << 7));
                uint4 p1 = *(const uint4*)(hb + ((size_t)s1 << 7));
                uint4 p2 = *(const uint4*)(hb + ((size_t)s2 << 7));
                uint4 p3 = *(const uint4*)(hb + ((size_t)s3 << 7));
                fma8r(au[u], p0, w0);
                fma8r(au[u], p1, w1);
                fma8r(au[u], p2, w2);
                fma8r(au[u], p3, w3);
            }
        }
    }
    // epilogue: +self, *dinv, +b1, relu, W2 dot, quad butterfly -> h2'
    float4 b1a = *(const float4*)(b1 + c16 * 8);
    float4 b1b = *(const float4*)(b1 + c16 * 8 + 4);
    const float4* wp = (const float4*)(W2 + c16 * 16);
    float4 w0 = wp[0], w1 = wp[1], w2 = wp[2], w3 = wp[3];
#pragma unroll
    for (int u = 0; u < 2; u++) {
        int d = dbase + u * 4 + g;
        int node = (b << BSH) + d;
        bool valid = node < N;
        float di = valid ? dinv[node] : 0.f;
        uint4 sp = make_uint4(0, 0, 0, 0);
        if (valid) sp = *(const uint4*)(h1b + ((size_t)node << 7) + c16 * 8);
        float e0 = fmaxf(fmaf(di, au[u][0] + bl(sp.x), b1a.x), 0.f);
        float e1 = fmaxf(fmaf(di, au[u][1] + bh(sp.x), b1a.y), 0.f);
        float e2 = fmaxf(fmaf(di, au[u][2] + bl(sp.y), b1a.z), 0.f);
        float e3 = fmaxf(fmaf(di, au[u][3] + bh(sp.y), b1a.w), 0.f);
        float e4 = fmaxf(fmaf(di, au[u][4] + bl(sp.z), b1b.x), 0.f);
        float e5 = fmaxf(fmaf(di, au[u][5] + bh(sp.z), b1b.y), 0.f);
        float e6 = fmaxf(fmaf(di, au[u][6] + bl(sp.w), b1b.z), 0.f);
        float e7 = fmaxf(fmaf(di, au[u][7] + bh(sp.w), b1b.w), 0.f);
        float s0 = e0 * w0.x + e1 * w0.z + e2 * w1.x + e3 * w1.z
                 + e4 * w2.x + e5 * w2.z + e6 * w3.x + e7 * w3.z;
        float s1 = e0 * w0.y + e1 * w0.w + e2 * w1.y + e3 * w1.w
                 + e4 * w2.y + e5 * w2.w + e6 * w3.y + e7 * w3.w;
#pragma unroll
        for (int dd = 1; dd < 16; dd <<= 1) {
            s0 += __shfl_xor(s0, dd);
            s1 += __shfl_xor(s1, dd);
        }
        if (c16 == 0 && valid)
            ((float2*)h2)[node] = make_float2(di * s0, di * s1);
    }
}

// ---- layer-2 aggregation: fine-CSR walk, 2 lanes/dst, 4-deep unroll --------
__global__ __launch_bounds__(256) void k_agg2(const int* __restrict__ rowfine,
                                              const unsigned* __restrict__ epack2,
                                              const float* __restrict__ h2,
                                              const float* __restrict__ dinv,
                                              const float* __restrict__ b2,
                                              float* __restrict__ out,
                                              int NCH, int K, int N) {
    __shared__ float a2[NB * 2];
    int b = blockIdx.x, t = threadIdx.x;
    int d = t & 127, half = t >> 7;
    int nk = NCH << BSH;
    const int* rfb = rowfine + (size_t)b * nk;
    float sx = 0.f, sy = 0.f;
    for (int ch = half; ch < NCH; ch += 2) {
        int jb = rfb[(ch << BSH) + d];
        int je = rfb[(ch << BSH) + d + 1];
        for (int j = jb; j < je; j += 4) {     // 4 gathers in flight
            int j1 = min(j + 1, je - 1);
            int j2 = min(j + 2, je - 1);
            int j3 = min(j + 3, je - 1);
            unsigned r0 = epack2[j],  r1 = epack2[j1];
            unsigned r2 = epack2[j2], r3 = epack2[j3];
            int s0, s1, s2, s3; float w0, w1, w2, w3;
            dec_edge(r0, s0, w0); dec_edge(r1, s1, w1);
            dec_edge(r2, s2, w2); dec_edge(r3, s3, w3);
            w1 = (j + 1 < je) ? w1 : 0.f;
            w2 = (j + 2 < je) ? w2 : 0.f;
            w3 = (j + 3 < je) ? w3 : 0.f;
            float2 v0 = ((const float2*)h2)[s0];
            float2 v1 = ((const float2*)h2)[s1];
            float2 v2 = ((const float2*)h2)[s2];
            float2 v3 = ((const float2*)h2)[s3];
            sx = fmaf(w0, v0.x, sx); sy = fmaf(w0, v0.y, sy);
            sx = fmaf(w1, v1.x, sx); sy = fmaf(w1, v1.y, sy);
            sx = fmaf(w2, v2.x, sx); sy = fmaf(w2, v2.y, sy);
            sx = fmaf(w3, v3.x, sx); sy = fmaf(w3, v3.y, sy);
        }
    }
    if (half == 1) { a2[d * 2] = sx; a2[d * 2 + 1] = sy; }
    __syncthreads();
    if (half == 0) {
        int node = (b << BSH) + d;
        if (node < N) {
            float di = dinv[node];
            float2 hv = ((const float2*)h2)[node];   // already dinv*H2
            sx += a2[d * 2]; sy += a2[d * 2 + 1];
            ((float2*)out)[node] = make_float2(b2[0] + di * (sx + hv.x),
                                               b2[1] + di * (sy + hv.y));
        }
    }
}

static inline size_t algn16(size_t v) { return (v + 15) & ~(size_t)15; }

extern "C" void kernel_launch(void* const* d_in, const int* in_sizes, int n_in,
                              void* d_out, int out_size, void* d_ws, size_t ws_size,
                              hipStream_t stream) {
    const float* x  = (const float*)d_in[0];
    const int*   ei = (const int*)d_in[1];   // [2,E] int32
    const float* ew = (const float*)d_in[2];
    const float* W1 = (const float*)d_in[3];
    const float* b1 = (const float*)d_in[4];
    const float* W2 = (const float*)d_in[5];
    const float* b2 = (const float*)d_in[6];
    float* out = (float*)d_out;

    int N = in_sizes[0] / IN_C;
    int E = in_sizes[2];
    int K = (N + NB - 1) >> BSH;             // buckets (782)
    int NCH = (N + (1 << CSH) - 1) >> CSH;   // src chunks (7)
    int nk = NCH << BSH;                     // fine keys per bucket (896)
    int W = 512;                             // pass-1 workgroups (2/CU)
    int CHv = (E + W - 1) / W;
    int KW = K * W;                          // coarse hist size (~400k)

    char* ws = (char*)d_ws;
    float* dinv    = (float*)ws; ws += algn16((size_t)N * 4);
    int*   gcnt    = (int*)ws;   ws += algn16((size_t)KW * 4);
    int*   bsum    = (int*)ws;   ws += 8192;
    int*   rowfine = (int*)ws;   ws += algn16(((size_t)K * nk + 1) * 4);
    unsigned* epack2 = (unsigned*)ws; ws += algn16((size_t)E * 4);
    // ebuf (E*8) and h1b (N*256) alias: sortfine consumes ebuf before gemm1
    size_t big = (size_t)E * 8;
    size_t h1sz = (size_t)N * HID_C * 2;
    if (h1sz > big) big = h1sz;
    int2* ebuf = (int2*)ws;
    unsigned short* h1b = (unsigned short*)ws; ws += algn16(big);
    unsigned short* w1t = (unsigned short*)ws; ws += algn16((size_t)HID_C * IN_C * 2);
    float* h2      = (float*)ws; ws += algn16((size_t)N * OUT_C * 4);

    int nb_s4 = (KW + 4095) / 4096;          // ~98 (<=2048 for k_scanB)
    size_t lds_k = (size_t)K * 4;            // ~3.1 KB dynamic LDS

    k_wT      <<<(HID_C * IN_C + 255) / 256, 256, 0, stream>>>(W1, w1t);
    k_count   <<<W, 256, lds_k, stream>>>(ei, gcnt, E, K, W, CHv);
    k_scanA4  <<<nb_s4, 256, 0, stream>>>(gcnt, gcnt, bsum, KW);
    k_scanB   <<<1, 256, 0, stream>>>(bsum, nb_s4);
    k_place   <<<W, 256, lds_k, stream>>>(ei, ew, gcnt, bsum, ebuf, E, K, W, CHv);
    k_sortfine<<<K, 512, 0, stream>>>(gcnt, bsum, ebuf, epack2, rowfine, dinv, W, NCH, E, K, N);
    k_gemm1   <<<(N + 127) / 128, 256, 0, stream>>>(x, w1t, dinv, h1b, N);
    k_agg1    <<<K * 2, 512, 0, stream>>>(rowfine, epack2, h1b, dinv, b1, W2, h2, NCH, K, N);
    k_agg2    <<<K, 256, 0, stream>>>(rowfine, epack2, h2, dinv, b2, out, NCH, K, N);
}